// Round 8
// baseline (728.896 us; speedup 1.0000x reference)
//
#include <hip/hip_runtime.h>
#include <math.h>

#define Nn 512
#define Ld 64
#define NB 8
#define C1 32
#define C2 25      // 3*NB+1

// ---- exact math (bit-identical to passing round-4/5 kernels) ----
__device__ __forceinline__ float gelu_tanh(float a) {
    float a3 = a * a * a;
    float t = tanhf(0.7978845608028654f * (a + 0.044715f * a3));
    return 0.5f * a * (1.0f + t);
}

__device__ __forceinline__ float softplus_f(float v) {
    return (v > 0.0f) ? v + log1pf(expf(-v)) : log1pf(expf(v));
}

__device__ __forceinline__ float pos_mod_2pi(float v) {
    const float T = 6.2831853071795864769f;
    float r = fmodf(v, T);
    if (r < 0.0f) r += T;
    return r;
}

// ============ K1: conv1 + gelu -> h1 CHANNEL-MINOR [n][row][col][c] ============
// Same compute order as r5/r6 K1 (c ascending, cos/sin interleaved per tap)
// -> h1 values bit-identical; only the memory layout changes.
__global__ __launch_bounds__(256) void k1_conv1_cm_kernel(
    const float* __restrict__ x,
    const float* __restrict__ c1w, const float* __restrict__ c1b,
    float* __restrict__ h1g)
{
    __shared__ float s_cos[8 * 69];
    __shared__ float s_sin[8 * 69];

    const int tid = threadIdx.x;
    const int rb  = blockIdx.x;      // 0..15 -> 4-row band
    const int n   = blockIdx.y;
    const int r0k = rb * 4;
    const float* xn = x + n * 4096;

    for (int idx = tid; idx < 8 * 68; idx += 256) {
        int li = idx / 68, lj = idx - li * 68;
        int gi = (r0k - 2 + li) & 63;
        int gj = (lj - 2) & 63;
        float xv = xn[gi * 64 + gj];
        int pat = (gi + 2 * gj) % 3;
        float sv, cv;
        sincosf(xv, &sv, &cv);
        float fz = (pat == 2) ? 1.0f : 0.0f;
        s_cos[li * 69 + lj] = fz * cv;
        s_sin[li * 69 + lj] = fz * sv;
    }
    __syncthreads();

    const int gj = tid & 63, lrow = tid >> 6;
    const int gi = r0k + lrow;

    float v[18];
    #pragma unroll
    for (int di = 0; di < 3; ++di)
        #pragma unroll
        for (int dj = 0; dj < 3; ++dj) {
            int a = (lrow + 1 + di) * 69 + (gj + 1 + dj);
            v[di * 3 + dj]     = s_cos[a];
            v[9 + di * 3 + dj] = s_sin[a];
        }

    // channel-minor: 32 consecutive floats per site, written as 8 float4s
    float* h1p = h1g + ((size_t)n * 4096 + gi * 64 + gj) * 32;
    #pragma unroll 2
    for (int cg = 0; cg < 8; ++cg) {
        float oo[4];
        #pragma unroll
        for (int cs = 0; cs < 4; ++cs) {
            int c = cg * 4 + cs;
            const float* w = c1w + c * 18;   // uniform -> s_load
            float a1 = c1b[c];
            #pragma unroll
            for (int t = 0; t < 9; ++t) {
                a1 = fmaf(v[t],     w[t],     a1);
                a1 = fmaf(v[9 + t], w[9 + t], a1);
            }
            oo[cs] = gelu_tanh(a1);
        }
        float4 o; o.x = oo[0]; o.y = oo[1]; o.z = oo[2]; o.w = oo[3];
        *(float4*)(h1p + cg * 4) = o;  // 8 stores/site fill both 64B sectors back-to-back
    }
}

// ============ K2: conv2 from global (channel-minor) + spline + logJ ============
// No LDS staging, no barriers in the channel loop: 9 neighborhood addresses
// computed once, float4 loads with offset:cb*16 immediates, pure per-thread ILP.
// (256,4): 128-reg cap -> acc[25]+v4[36]+addr[18] fits, no spills (r7 lesson).
__global__ __launch_bounds__(256, 4) void k2_conv2_spline_cm_kernel(
    const float* __restrict__ x, const float* __restrict__ h1g,
    const float* __restrict__ c2w, const float* __restrict__ c2b,
    float* __restrict__ out_fx, float* __restrict__ out_logJ)
{
    __shared__ float s_red[4];

    const float TWO_PI_F = 6.2831853071795864769f;

    const int tid  = threadIdx.x;
    const int band = blockIdx.x;            // 0..5
    const int n    = blockIdx.y;
    const int r0   = band * 12;
    const int R    = (band == 5) ? 4 : 12;
    const int n_active = (R == 12) ? 256 : 86;
    const float* xn  = x + n * 4096;
    const float* h1n = h1g + (size_t)n * 4096 * 32;

    // active-site mapping: rows 3g,3g+1,3g+2 hold 22,21,21 actives, col≡row mod 3
    int g3 = tid >> 6, u = tid & 63;
    int rsel  = (u >= 22) + (u >= 43);
    int ubase = (rsel == 2) ? 43 : ((rsel == 1) ? 22 : 0);
    int rr = 3 * g3 + rsel;                 // local band row
    int cc = 3 * (u - ubase) + rsel;        // global col
    bool is_act = (tid < n_active);
    int jm = (cc + 63) & 63, jp = (cc + 1) & 63;

    float acc[C2];
    #pragma unroll
    for (int co = 0; co < C2; ++co) acc[co] = c2b[co];

    if (is_act) {
        int gi = r0 + rr;
        int rows[3] = { (gi + 63) & 63, gi, (gi + 1) & 63 };
        int cols[3] = { jm, cc, jp };
        const float* p[9];
        #pragma unroll
        for (int di = 0; di < 3; ++di)
            #pragma unroll
            for (int dj = 0; dj < 3; ++dj)
                p[di * 3 + dj] = h1n + ((size_t)(rows[di] * 64 + cols[dj])) * 32;

        #pragma unroll 1
        for (int cb = 0; cb < 8; ++cb) {
            float arr[36];
            #pragma unroll
            for (int t = 0; t < 9; ++t)
                *(float4*)(&arr[t * 4]) = *(const float4*)(p[t] + cb * 4);
            #pragma unroll
            for (int cs = 0; cs < 4; ++cs) {
                const float* wp = c2w + (cb * 4 + cs) * 9;   // ci = cb*4+cs ascending
                #pragma unroll
                for (int co = 0; co < C2; ++co) {
                    const float* w = wp + co * (C1 * 9);     // uniform -> s_load
                    float a2 = acc[co];
                    #pragma unroll
                    for (int t = 0; t < 9; ++t) a2 = fmaf(arr[t * 4 + cs], w[t], a2);
                    acc[co] = a2;
                }
            }
        }
    }

    // ---- passive/frozen pass-through ----
    float* outn = out_fx + n * 4096;
    for (int idx = tid; idx < R * 64; idx += 256) {
        int lr = idx >> 6, c = idx & 63;
        int gi = r0 + lr;
        int pat = (gi + 2 * c) % 3;
        float xv = xn[gi * 64 + c];
        if (pat != 0) outn[gi * 64 + c] = xv;
    }

    // ---- spline at the active site (exact math, r4-identical) ----
    float lj_val = 0.0f;
    if (is_act) {
        int gi = r0 + rr;
        float xv = xn[gi * 64 + cc];

        float kx[NB + 1], ky[NB + 1], sar[NB + 1];
        {
            float m = acc[0];
            #pragma unroll
            for (int q = 1; q < NB; ++q) m = fmaxf(m, acc[q]);
            float e[NB], ssum = 0.0f;
            #pragma unroll
            for (int q = 0; q < NB; ++q) { e[q] = expf(acc[q] - m); ssum += e[q]; }
            float inv = TWO_PI_F / ssum;
            float run = 0.0f;
            kx[0] = 0.0f;
            #pragma unroll
            for (int q = 0; q < NB; ++q) { run += e[q]; kx[q + 1] = run * inv; }
        }
        {
            float m = acc[NB];
            #pragma unroll
            for (int q = 1; q < NB; ++q) m = fmaxf(m, acc[NB + q]);
            float e[NB], ssum = 0.0f;
            #pragma unroll
            for (int q = 0; q < NB; ++q) { e[q] = expf(acc[NB + q] - m); ssum += e[q]; }
            float inv = TWO_PI_F / ssum;
            float run = 0.0f;
            ky[0] = 0.0f;
            #pragma unroll
            for (int q = 0; q < NB; ++q) { run += e[q]; ky[q + 1] = run * inv; }
        }
        #pragma unroll
        for (int q = 0; q < NB; ++q) sar[q] = softplus_f(acc[2 * NB + q]);
        sar[NB] = sar[0];
        float t_out = acc[3 * NB];

        float x1 = pos_mod_2pi(xv);
        int k = 0;
        #pragma unroll
        for (int q = 1; q <= NB - 1; ++q) k += (x1 >= kx[q]) ? 1 : 0;

        float kxk = 0.f, kxk1 = 0.f, kyk = 0.f, kyk1 = 0.f, sk = 0.f, sk1 = 0.f;
        #pragma unroll
        for (int q = 0; q <= NB; ++q) {
            if (q == k)     { kxk = kx[q];  kyk = ky[q];  sk  = sar[q]; }
            if (q == k + 1) { kxk1 = kx[q]; kyk1 = ky[q]; sk1 = sar[q]; }
        }

        float wk = kxk1 - kxk;
        float hk = kyk1 - kyk;
        float slope = hk / wk;
        float xi = (x1 - kxk) / wk;
        xi = fminf(fmaxf(xi, 0.0f), 1.0f);
        float om = 1.0f - xi;
        float den = slope + (sk1 + sk - 2.0f * slope) * xi * om;
        float y = kyk + hk * (slope * xi * xi + sk * xi * om) / den;
        float num = slope * slope * (sk1 * xi * xi + 2.0f * slope * xi * om + sk * om * om);
        lj_val = logf(num) - 2.0f * logf(den);

        outn[gi * 64 + cc] = pos_mod_2pi(y + t_out);
    }

    // ---- logJ: wave shuffle -> LDS -> one atomic per block ----
    float r = lj_val;
    #pragma unroll
    for (int off = 32; off > 0; off >>= 1) r += __shfl_down(r, off, 64);
    int lane = tid & 63, wv = tid >> 6;
    if (lane == 0) s_red[wv] = r;
    __syncthreads();
    if (tid == 0)
        atomicAdd(&out_logJ[n], s_red[0] + s_red[1] + s_red[2] + s_red[3]);
}

// ================= fallback: round-4 fused kernel (if ws too small) =================
#define CHUNK 8
#define ICOLS 68
#define ISTR  69
#define IROWSMAX 16
#define HCOLS 66
#define HSTR  67
#define HPLANE 945

__global__ __launch_bounds__(256, 4) void csplaq_v4_kernel(
    const float* __restrict__ x,
    const float* __restrict__ c1w, const float* __restrict__ c1b,
    const float* __restrict__ c2w, const float* __restrict__ c2b,
    float* __restrict__ out_fx, float* __restrict__ out_logJ)
{
    __shared__ float s_cos[IROWSMAX * ISTR];
    __shared__ float s_sin[IROWSMAX * ISTR];
    __shared__ float s_h1[CHUNK * HPLANE];
    __shared__ float s_red[4];

    const float TWO_PI_F = 6.2831853071795864769f;
    const int tid  = threadIdx.x;
    const int band = blockIdx.x;
    const int n    = blockIdx.y;
    const int r0   = band * 12;
    const int R    = (band == 5) ? 4 : 12;
    const int rows_in  = R + 4;
    const int nsite_h  = (R + 2) * HCOLS;
    const int n_active = (R == 12) ? 256 : 86;
    const float* xn = x + n * Ld * Ld;

    for (int idx = tid; idx < rows_in * ICOLS; idx += 256) {
        int li = idx / ICOLS, uu = idx - li * ICOLS;
        int gi = (r0 - 2 + li) & 63;
        int gj = (uu - 2) & 63;
        float xv = xn[gi * Ld + gj];
        int pat = (gi + 2 * gj) % 3;
        float sv, cv;
        sincosf(xv, &sv, &cv);
        float fz = (pat == 2) ? 1.0f : 0.0f;
        s_cos[li * ISTR + uu] = fz * cv;
        s_sin[li * ISTR + uu] = fz * sv;
    }

    int g3 = tid >> 6, u = tid & 63;
    int rsel  = (u >= 22) + (u >= 43);
    int ubase = (rsel == 2) ? 43 : ((rsel == 1) ? 22 : 0);
    int rr = 3 * g3 + rsel;
    int cc = 3 * (u - ubase) + rsel;
    bool is_act = (tid < n_active);

    float acc[C2];
    #pragma unroll
    for (int co = 0; co < C2; ++co) acc[co] = c2b[co];

    for (int c0 = 0; c0 < C1; c0 += CHUNK) {
        __syncthreads();
        for (int s = tid; s < nsite_h; s += 256) {
            int h = s / HCOLS, j = s - h * HCOLS;
            float v[18];
            #pragma unroll
            for (int di = 0; di < 3; ++di)
                #pragma unroll
                for (int dj = 0; dj < 3; ++dj) {
                    int a = (h + di) * ISTR + (j + dj);
                    v[di * 3 + dj]     = s_cos[a];
                    v[9 + di * 3 + dj] = s_sin[a];
                }
            #pragma unroll
            for (int c = 0; c < CHUNK; ++c) {
                const float* w = c1w + (c0 + c) * 18;
                float a1 = c1b[c0 + c];
                #pragma unroll
                for (int t = 0; t < 9; ++t) {
                    a1 = fmaf(v[t],     w[t],     a1);
                    a1 = fmaf(v[9 + t], w[9 + t], a1);
                }
                s_h1[c * HPLANE + h * HSTR + j] = gelu_tanh(a1);
            }
        }
        __syncthreads();
        if (is_act) {
            #pragma unroll 1
            for (int c = 0; c < CHUNK; ++c) {
                int ci = c0 + c;
                float v[9];
                const float* hp = s_h1 + c * HPLANE + rr * HSTR + cc;
                #pragma unroll
                for (int di = 0; di < 3; ++di)
                    #pragma unroll
                    for (int dj = 0; dj < 3; ++dj)
                        v[di * 3 + dj] = hp[di * HSTR + dj];
                const float* wp = c2w + ci * 9;
                #pragma unroll
                for (int co = 0; co < C2; ++co) {
                    const float* w = wp + co * (C1 * 9);
                    float a2 = acc[co];
                    #pragma unroll
                    for (int t = 0; t < 9; ++t) a2 = fmaf(v[t], w[t], a2);
                    acc[co] = a2;
                }
            }
        }
    }

    float* outn = out_fx + n * Ld * Ld;
    for (int idx = tid; idx < R * 64; idx += 256) {
        int lr = idx >> 6, c = idx & 63;
        int gi = r0 + lr;
        int pat = (gi + 2 * c) % 3;
        float xv = xn[gi * Ld + c];
        if (pat != 0) outn[gi * Ld + c] = xv;
    }

    float lj_val = 0.0f;
    if (is_act) {
        int gi = r0 + rr;
        float xv = xn[gi * Ld + cc];
        float kx[NB + 1], ky[NB + 1], sar[NB + 1];
        {
            float m = acc[0];
            #pragma unroll
            for (int q = 1; q < NB; ++q) m = fmaxf(m, acc[q]);
            float e[NB], ssum = 0.0f;
            #pragma unroll
            for (int q = 0; q < NB; ++q) { e[q] = expf(acc[q] - m); ssum += e[q]; }
            float inv = TWO_PI_F / ssum;
            float run = 0.0f;
            kx[0] = 0.0f;
            #pragma unroll
            for (int q = 0; q < NB; ++q) { run += e[q]; kx[q + 1] = run * inv; }
        }
        {
            float m = acc[NB];
            #pragma unroll
            for (int q = 1; q < NB; ++q) m = fmaxf(m, acc[NB + q]);
            float e[NB], ssum = 0.0f;
            #pragma unroll
            for (int q = 0; q < NB; ++q) { e[q] = expf(acc[NB + q] - m); ssum += e[q]; }
            float inv = TWO_PI_F / ssum;
            float run = 0.0f;
            ky[0] = 0.0f;
            #pragma unroll
            for (int q = 0; q < NB; ++q) { run += e[q]; ky[q + 1] = run * inv; }
        }
        #pragma unroll
        for (int q = 0; q < NB; ++q) sar[q] = softplus_f(acc[2 * NB + q]);
        sar[NB] = sar[0];
        float t_out = acc[3 * NB];

        float x1 = pos_mod_2pi(xv);
        int k = 0;
        #pragma unroll
        for (int q = 1; q <= NB - 1; ++q) k += (x1 >= kx[q]) ? 1 : 0;

        float kxk = 0.f, kxk1 = 0.f, kyk = 0.f, kyk1 = 0.f, sk = 0.f, sk1 = 0.f;
        #pragma unroll
        for (int q = 0; q <= NB; ++q) {
            if (q == k)     { kxk = kx[q];  kyk = ky[q];  sk  = sar[q]; }
            if (q == k + 1) { kxk1 = kx[q]; kyk1 = ky[q]; sk1 = sar[q]; }
        }

        float wk = kxk1 - kxk;
        float hk = kyk1 - kyk;
        float slope = hk / wk;
        float xi = (x1 - kxk) / wk;
        xi = fminf(fmaxf(xi, 0.0f), 1.0f);
        float om = 1.0f - xi;
        float den = slope + (sk1 + sk - 2.0f * slope) * xi * om;
        float y = kyk + hk * (slope * xi * xi + sk * xi * om) / den;
        float num = slope * slope * (sk1 * xi * xi + 2.0f * slope * xi * om + sk * om * om);
        lj_val = logf(num) - 2.0f * logf(den);

        outn[gi * Ld + cc] = pos_mod_2pi(y + t_out);
    }

    float r = lj_val;
    #pragma unroll
    for (int off = 32; off > 0; off >>= 1) r += __shfl_down(r, off, 64);
    int lane = tid & 63, wv = tid >> 6;
    if (lane == 0) s_red[wv] = r;
    __syncthreads();
    if (tid == 0)
        atomicAdd(&out_logJ[n], s_red[0] + s_red[1] + s_red[2] + s_red[3]);
}

extern "C" void kernel_launch(void* const* d_in, const int* in_sizes, int n_in,
                              void* d_out, int out_size, void* d_ws, size_t ws_size,
                              hipStream_t stream) {
    const float* x   = (const float*)d_in[0];
    // d_in[1..3] masks: recomputed analytically ((i+2j)%3) -> exact
    const float* c1w = (const float*)d_in[4];
    const float* c1b = (const float*)d_in[5];
    const float* c2w = (const float*)d_in[6];
    const float* c2b = (const float*)d_in[7];

    float* out_fx   = (float*)d_out;
    float* out_logJ = out_fx + (size_t)Nn * Ld * Ld;

    hipMemsetAsync(out_logJ, 0, Nn * sizeof(float), stream);

    const size_t h1_bytes = (size_t)Nn * C1 * Ld * Ld * sizeof(float);  // 256 MiB
    if (ws_size >= h1_bytes) {
        float* h1g = (float*)d_ws;
        dim3 g1(16, Nn);
        k1_conv1_cm_kernel<<<g1, 256, 0, stream>>>(x, c1w, c1b, h1g);
        dim3 g2(6, Nn);
        k2_conv2_spline_cm_kernel<<<g2, 256, 0, stream>>>(x, h1g, c2w, c2b, out_fx, out_logJ);
    } else {
        dim3 grid(6, Nn);
        csplaq_v4_kernel<<<grid, 256, 0, stream>>>(x, c1w, c1b, c2w, c2b, out_fx, out_logJ);
    }
}

// Round 9
// 503.387 us; speedup vs baseline: 1.4480x; 1.4480x over previous
//
#include <hip/hip_runtime.h>
#include <math.h>

#define Nn 512
#define Ld 64
#define NB 8
#define C1 32
#define C2 25      // 3*NB+1

// ---- exact math (bit-identical to passing round-4/5 kernels) ----
__device__ __forceinline__ float gelu_tanh(float a) {
    float a3 = a * a * a;
    float t = tanhf(0.7978845608028654f * (a + 0.044715f * a3));
    return 0.5f * a * (1.0f + t);
}

__device__ __forceinline__ float softplus_f(float v) {
    return (v > 0.0f) ? v + log1pf(expf(-v)) : log1pf(expf(v));
}

__device__ __forceinline__ float pos_mod_2pi(float v) {
    const float T = 6.2831853071795864769f;
    float r = fmodf(v, T);
    if (r < 0.0f) r += T;
    return r;
}

// ================= K1: conv1 + gelu -> global h1 [n][c][64][64] =================
// r6 config (unbounded): measured 104 us vs 117 us bounded.
__global__ __launch_bounds__(256) void k1_conv1_kernel(
    const float* __restrict__ x,
    const float* __restrict__ c1w, const float* __restrict__ c1b,
    float* __restrict__ h1g)
{
    __shared__ float s_cos[8 * 69];
    __shared__ float s_sin[8 * 69];

    const int tid = threadIdx.x;
    const int rb  = blockIdx.x;      // 0..15 -> 4-row band
    const int n   = blockIdx.y;
    const int r0k = rb * 4;
    const float* xn = x + n * 4096;

    for (int idx = tid; idx < 8 * 68; idx += 256) {
        int li = idx / 68, lj = idx - li * 68;
        int gi = (r0k - 2 + li) & 63;
        int gj = (lj - 2) & 63;
        float xv = xn[gi * 64 + gj];
        int pat = (gi + 2 * gj) % 3;
        float sv, cv;
        sincosf(xv, &sv, &cv);
        float fz = (pat == 2) ? 1.0f : 0.0f;
        s_cos[li * 69 + lj] = fz * cv;
        s_sin[li * 69 + lj] = fz * sv;
    }
    __syncthreads();

    const int gj = tid & 63, lrow = tid >> 6;
    const int gi = r0k + lrow;

    float v[18];
    #pragma unroll
    for (int di = 0; di < 3; ++di)
        #pragma unroll
        for (int dj = 0; dj < 3; ++dj) {
            int a = (lrow + 1 + di) * 69 + (gj + 1 + dj);
            v[di * 3 + dj]     = s_cos[a];
            v[9 + di * 3 + dj] = s_sin[a];
        }

    float* outp = h1g + (size_t)n * C1 * 4096 + gi * 64 + gj;
    #pragma unroll 4
    for (int c = 0; c < C1; ++c) {
        const float* w = c1w + c * 18;   // uniform -> s_load
        float a1 = c1b[c];
        #pragma unroll
        for (int t = 0; t < 9; ++t) {    // cos/sin interleaved per tap == r4 order
            a1 = fmaf(v[t],     w[t],     a1);
            a1 = fmaf(v[9 + t], w[9 + t], a1);
        }
        outp[(size_t)c * 4096] = gelu_tanh(a1);
    }
}

// ================= K2: conv2 + spline, DOUBLE-BUFFERED LDS staging =================
// r5 structure + dbuf pipeline: issue next-chunk loads -> compute -> regs->LDS(other
// buffer) -> ONE barrier. (256,5): 102-reg cap, pf[4] fits (r7 spilled at 64-cap).
// Always stage 14 rows (band 5 wraps, extra rows unused) -> fstride=224 compile-time.
#define K2CH 4
#define K2PLANE (14 * 64)   // 896 floats per staged channel plane
#define K2NF4  896          // float4s per chunk (4 planes * 224)

__global__ __launch_bounds__(256, 5) void k2_conv2_spline_db_kernel(
    const float* __restrict__ x, const float* __restrict__ h1g,
    const float* __restrict__ c2w, const float* __restrict__ c2b,
    float* __restrict__ out_fx, float* __restrict__ out_logJ)
{
    __shared__ float s_a[K2CH * K2PLANE];   // 14336 B
    __shared__ float s_b[K2CH * K2PLANE];   // 14336 B
    __shared__ float s_red[4];

    const float TWO_PI_F = 6.2831853071795864769f;

    const int tid  = threadIdx.x;
    const int band = blockIdx.x;            // 0..5
    const int n    = blockIdx.y;
    const int r0   = band * 12;
    const int R    = (band == 5) ? 4 : 12;
    const int n_active = (R == 12) ? 256 : 86;
    const float* xn  = x + n * 4096;
    const float* h1n = h1g + (size_t)n * C1 * 4096;

    // active-site mapping: rows 3g,3g+1,3g+2 hold 22,21,21 actives, col≡row mod 3
    int g3 = tid >> 6, u = tid & 63;
    int rsel  = (u >= 22) + (u >= 43);
    int ubase = (rsel == 2) ? 43 : ((rsel == 1) ? 22 : 0);
    int rr = 3 * g3 + rsel;                 // local band row
    int cc = 3 * (u - ubase) + rsel;        // global col
    bool is_act = (tid < n_active);
    int jm = (cc + 63) & 63, jp = (cc + 1) & 63;

    // per-lane staging coords (compile-time 224 divisor -> magic mul)
    int sc[4], soff[4];     // channel-within-chunk, LDS float offset
    int grow[4];            // wrapped global row
    #pragma unroll
    for (int k = 0; k < 4; ++k) {
        int f = tid + k * 256;
        int c = f / 224; int rem = f - c * 224;
        sc[k] = c;
        soff[k] = c * K2PLANE + (rem >> 4) * 64 + (rem & 15) * 4;
        grow[k] = (r0 - 1 + (rem >> 4)) & 63;
        // gcol4 = rem & 15
    }

    float acc[C2];
    #pragma unroll
    for (int co = 0; co < C2; ++co) acc[co] = c2b[co];

    // ---- prologue: chunk 0 -> pf -> buffer A ----
    float4 pf[4];
    #pragma unroll
    for (int k = 0; k < 4; ++k) {
        int f = tid + k * 256;
        if (f < K2NF4)
            pf[k] = *(const float4*)(h1n + (size_t)sc[k] * 4096 + grow[k] * 64 + ((f - sc[k] * 224) & 15) * 4);
    }
    #pragma unroll
    for (int k = 0; k < 4; ++k) {
        int f = tid + k * 256;
        if (f < K2NF4) *(float4*)(&s_a[soff[k]]) = pf[k];
    }
    __syncthreads();

    int cur = 0;
    for (int c0 = 0; c0 < C1; c0 += K2CH) {
        // issue next chunk's global loads (latency overlaps compute below)
        bool more = (c0 + K2CH < C1);
        if (more) {
            #pragma unroll
            for (int k = 0; k < 4; ++k) {
                int f = tid + k * 256;
                if (f < K2NF4)
                    pf[k] = *(const float4*)(h1n + (size_t)(c0 + K2CH + sc[k]) * 4096 + grow[k] * 64 + ((f - sc[k] * 224) & 15) * 4);
            }
        }
        const float* sbuf = cur ? s_b : s_a;
        if (is_act) {
            #pragma unroll 1
            for (int c = 0; c < K2CH; ++c) {
                int ci = c0 + c;
                float v[9];
                #pragma unroll
                for (int di = 0; di < 3; ++di) {
                    const float* rowp = sbuf + c * K2PLANE + (rr + di) * 64;
                    v[di * 3 + 0] = rowp[jm];
                    v[di * 3 + 1] = rowp[cc];
                    v[di * 3 + 2] = rowp[jp];
                }
                const float* wp = c2w + ci * 9;
                #pragma unroll
                for (int co = 0; co < C2; ++co) {
                    const float* w = wp + co * (C1 * 9);  // uniform -> s_load
                    float a2 = acc[co];
                    #pragma unroll
                    for (int t = 0; t < 9; ++t) a2 = fmaf(v[t], w[t], a2);
                    acc[co] = a2;
                }
            }
        }
        if (more) {
            float* dbuf = cur ? s_a : s_b;
            #pragma unroll
            for (int k = 0; k < 4; ++k) {
                int f = tid + k * 256;
                if (f < K2NF4) *(float4*)(&dbuf[soff[k]]) = pf[k];
            }
        }
        __syncthreads();
        cur ^= 1;
    }

    // ---- passive/frozen pass-through ----
    float* outn = out_fx + n * 4096;
    for (int idx = tid; idx < R * 64; idx += 256) {
        int lr = idx >> 6, c = idx & 63;
        int gi = r0 + lr;
        int pat = (gi + 2 * c) % 3;
        float xv = xn[gi * 64 + c];
        if (pat != 0) outn[gi * 64 + c] = xv;
    }

    // ---- spline at the active site (exact math, r4-identical) ----
    float lj_val = 0.0f;
    if (is_act) {
        int gi = r0 + rr;
        float xv = xn[gi * 64 + cc];

        float kx[NB + 1], ky[NB + 1], sar[NB + 1];
        {
            float m = acc[0];
            #pragma unroll
            for (int q = 1; q < NB; ++q) m = fmaxf(m, acc[q]);
            float e[NB], ssum = 0.0f;
            #pragma unroll
            for (int q = 0; q < NB; ++q) { e[q] = expf(acc[q] - m); ssum += e[q]; }
            float inv = TWO_PI_F / ssum;
            float run = 0.0f;
            kx[0] = 0.0f;
            #pragma unroll
            for (int q = 0; q < NB; ++q) { run += e[q]; kx[q + 1] = run * inv; }
        }
        {
            float m = acc[NB];
            #pragma unroll
            for (int q = 1; q < NB; ++q) m = fmaxf(m, acc[NB + q]);
            float e[NB], ssum = 0.0f;
            #pragma unroll
            for (int q = 0; q < NB; ++q) { e[q] = expf(acc[NB + q] - m); ssum += e[q]; }
            float inv = TWO_PI_F / ssum;
            float run = 0.0f;
            ky[0] = 0.0f;
            #pragma unroll
            for (int q = 0; q < NB; ++q) { run += e[q]; ky[q + 1] = run * inv; }
        }
        #pragma unroll
        for (int q = 0; q < NB; ++q) sar[q] = softplus_f(acc[2 * NB + q]);
        sar[NB] = sar[0];
        float t_out = acc[3 * NB];

        float x1 = pos_mod_2pi(xv);
        int k = 0;
        #pragma unroll
        for (int q = 1; q <= NB - 1; ++q) k += (x1 >= kx[q]) ? 1 : 0;

        float kxk = 0.f, kxk1 = 0.f, kyk = 0.f, kyk1 = 0.f, sk = 0.f, sk1 = 0.f;
        #pragma unroll
        for (int q = 0; q <= NB; ++q) {
            if (q == k)     { kxk = kx[q];  kyk = ky[q];  sk  = sar[q]; }
            if (q == k + 1) { kxk1 = kx[q]; kyk1 = ky[q]; sk1 = sar[q]; }
        }

        float wk = kxk1 - kxk;
        float hk = kyk1 - kyk;
        float slope = hk / wk;
        float xi = (x1 - kxk) / wk;
        xi = fminf(fmaxf(xi, 0.0f), 1.0f);
        float om = 1.0f - xi;
        float den = slope + (sk1 + sk - 2.0f * slope) * xi * om;
        float y = kyk + hk * (slope * xi * xi + sk * xi * om) / den;
        float num = slope * slope * (sk1 * xi * xi + 2.0f * slope * xi * om + sk * om * om);
        lj_val = logf(num) - 2.0f * logf(den);

        outn[gi * 64 + cc] = pos_mod_2pi(y + t_out);
    }

    // ---- logJ: wave shuffle -> LDS -> one atomic per block ----
    float r = lj_val;
    #pragma unroll
    for (int off = 32; off > 0; off >>= 1) r += __shfl_down(r, off, 64);
    int lane = tid & 63, wv = tid >> 6;
    if (lane == 0) s_red[wv] = r;
    __syncthreads();
    if (tid == 0)
        atomicAdd(&out_logJ[n], s_red[0] + s_red[1] + s_red[2] + s_red[3]);
}

// ================= fallback: round-4 fused kernel (if ws too small) =================
#define CHUNK 8
#define ICOLS 68
#define ISTR  69
#define IROWSMAX 16
#define HCOLS 66
#define HSTR  67
#define HPLANE 945

__global__ __launch_bounds__(256, 4) void csplaq_v4_kernel(
    const float* __restrict__ x,
    const float* __restrict__ c1w, const float* __restrict__ c1b,
    const float* __restrict__ c2w, const float* __restrict__ c2b,
    float* __restrict__ out_fx, float* __restrict__ out_logJ)
{
    __shared__ float s_cos[IROWSMAX * ISTR];
    __shared__ float s_sin[IROWSMAX * ISTR];
    __shared__ float s_h1[CHUNK * HPLANE];
    __shared__ float s_red[4];

    const float TWO_PI_F = 6.2831853071795864769f;
    const int tid  = threadIdx.x;
    const int band = blockIdx.x;
    const int n    = blockIdx.y;
    const int r0   = band * 12;
    const int R    = (band == 5) ? 4 : 12;
    const int rows_in  = R + 4;
    const int nsite_h  = (R + 2) * HCOLS;
    const int n_active = (R == 12) ? 256 : 86;
    const float* xn = x + n * Ld * Ld;

    for (int idx = tid; idx < rows_in * ICOLS; idx += 256) {
        int li = idx / ICOLS, uu = idx - li * ICOLS;
        int gi = (r0 - 2 + li) & 63;
        int gj = (uu - 2) & 63;
        float xv = xn[gi * Ld + gj];
        int pat = (gi + 2 * gj) % 3;
        float sv, cv;
        sincosf(xv, &sv, &cv);
        float fz = (pat == 2) ? 1.0f : 0.0f;
        s_cos[li * ISTR + uu] = fz * cv;
        s_sin[li * ISTR + uu] = fz * sv;
    }

    int g3 = tid >> 6, u = tid & 63;
    int rsel  = (u >= 22) + (u >= 43);
    int ubase = (rsel == 2) ? 43 : ((rsel == 1) ? 22 : 0);
    int rr = 3 * g3 + rsel;
    int cc = 3 * (u - ubase) + rsel;
    bool is_act = (tid < n_active);

    float acc[C2];
    #pragma unroll
    for (int co = 0; co < C2; ++co) acc[co] = c2b[co];

    for (int c0 = 0; c0 < C1; c0 += CHUNK) {
        __syncthreads();
        for (int s = tid; s < nsite_h; s += 256) {
            int h = s / HCOLS, j = s - h * HCOLS;
            float v[18];
            #pragma unroll
            for (int di = 0; di < 3; ++di)
                #pragma unroll
                for (int dj = 0; dj < 3; ++dj) {
                    int a = (h + di) * ISTR + (j + dj);
                    v[di * 3 + dj]     = s_cos[a];
                    v[9 + di * 3 + dj] = s_sin[a];
                }
            #pragma unroll
            for (int c = 0; c < CHUNK; ++c) {
                const float* w = c1w + (c0 + c) * 18;
                float a1 = c1b[c0 + c];
                #pragma unroll
                for (int t = 0; t < 9; ++t) {
                    a1 = fmaf(v[t],     w[t],     a1);
                    a1 = fmaf(v[9 + t], w[9 + t], a1);
                }
                s_h1[c * HPLANE + h * HSTR + j] = gelu_tanh(a1);
            }
        }
        __syncthreads();
        if (is_act) {
            #pragma unroll 1
            for (int c = 0; c < CHUNK; ++c) {
                int ci = c0 + c;
                float v[9];
                const float* hp = s_h1 + c * HPLANE + rr * HSTR + cc;
                #pragma unroll
                for (int di = 0; di < 3; ++di)
                    #pragma unroll
                    for (int dj = 0; dj < 3; ++dj)
                        v[di * 3 + dj] = hp[di * HSTR + dj];
                const float* wp = c2w + ci * 9;
                #pragma unroll
                for (int co = 0; co < C2; ++co) {
                    const float* w = wp + co * (C1 * 9);
                    float a2 = acc[co];
                    #pragma unroll
                    for (int t = 0; t < 9; ++t) a2 = fmaf(v[t], w[t], a2);
                    acc[co] = a2;
                }
            }
        }
    }

    float* outn = out_fx + n * Ld * Ld;
    for (int idx = tid; idx < R * 64; idx += 256) {
        int lr = idx >> 6, c = idx & 63;
        int gi = r0 + lr;
        int pat = (gi + 2 * c) % 3;
        float xv = xn[gi * Ld + c];
        if (pat != 0) outn[gi * Ld + c] = xv;
    }

    float lj_val = 0.0f;
    if (is_act) {
        int gi = r0 + rr;
        float xv = xn[gi * Ld + cc];
        float kx[NB + 1], ky[NB + 1], sar[NB + 1];
        {
            float m = acc[0];
            #pragma unroll
            for (int q = 1; q < NB; ++q) m = fmaxf(m, acc[q]);
            float e[NB], ssum = 0.0f;
            #pragma unroll
            for (int q = 0; q < NB; ++q) { e[q] = expf(acc[q] - m); ssum += e[q]; }
            float inv = TWO_PI_F / ssum;
            float run = 0.0f;
            kx[0] = 0.0f;
            #pragma unroll
            for (int q = 0; q < NB; ++q) { run += e[q]; kx[q + 1] = run * inv; }
        }
        {
            float m = acc[NB];
            #pragma unroll
            for (int q = 1; q < NB; ++q) m = fmaxf(m, acc[NB + q]);
            float e[NB], ssum = 0.0f;
            #pragma unroll
            for (int q = 0; q < NB; ++q) { e[q] = expf(acc[NB + q] - m); ssum += e[q]; }
            float inv = TWO_PI_F / ssum;
            float run = 0.0f;
            ky[0] = 0.0f;
            #pragma unroll
            for (int q = 0; q < NB; ++q) { run += e[q]; ky[q + 1] = run * inv; }
        }
        #pragma unroll
        for (int q = 0; q < NB; ++q) sar[q] = softplus_f(acc[2 * NB + q]);
        sar[NB] = sar[0];
        float t_out = acc[3 * NB];

        float x1 = pos_mod_2pi(xv);
        int k = 0;
        #pragma unroll
        for (int q = 1; q <= NB - 1; ++q) k += (x1 >= kx[q]) ? 1 : 0;

        float kxk = 0.f, kxk1 = 0.f, kyk = 0.f, kyk1 = 0.f, sk = 0.f, sk1 = 0.f;
        #pragma unroll
        for (int q = 0; q <= NB; ++q) {
            if (q == k)     { kxk = kx[q];  kyk = ky[q];  sk  = sar[q]; }
            if (q == k + 1) { kxk1 = kx[q]; kyk1 = ky[q]; sk1 = sar[q]; }
        }

        float wk = kxk1 - kxk;
        float hk = kyk1 - kyk;
        float slope = hk / wk;
        float xi = (x1 - kxk) / wk;
        xi = fminf(fmaxf(xi, 0.0f), 1.0f);
        float om = 1.0f - xi;
        float den = slope + (sk1 + sk - 2.0f * slope) * xi * om;
        float y = kyk + hk * (slope * xi * xi + sk * xi * om) / den;
        float num = slope * slope * (sk1 * xi * xi + 2.0f * slope * xi * om + sk * om * om);
        lj_val = logf(num) - 2.0f * logf(den);

        outn[gi * Ld + cc] = pos_mod_2pi(y + t_out);
    }

    float r = lj_val;
    #pragma unroll
    for (int off = 32; off > 0; off >>= 1) r += __shfl_down(r, off, 64);
    int lane = tid & 63, wv = tid >> 6;
    if (lane == 0) s_red[wv] = r;
    __syncthreads();
    if (tid == 0)
        atomicAdd(&out_logJ[n], s_red[0] + s_red[1] + s_red[2] + s_red[3]);
}

extern "C" void kernel_launch(void* const* d_in, const int* in_sizes, int n_in,
                              void* d_out, int out_size, void* d_ws, size_t ws_size,
                              hipStream_t stream) {
    const float* x   = (const float*)d_in[0];
    // d_in[1..3] masks: recomputed analytically ((i+2j)%3) -> exact
    const float* c1w = (const float*)d_in[4];
    const float* c1b = (const float*)d_in[5];
    const float* c2w = (const float*)d_in[6];
    const float* c2b = (const float*)d_in[7];

    float* out_fx   = (float*)d_out;
    float* out_logJ = out_fx + (size_t)Nn * Ld * Ld;

    hipMemsetAsync(out_logJ, 0, Nn * sizeof(float), stream);

    const size_t h1_bytes = (size_t)Nn * C1 * Ld * Ld * sizeof(float);  // 256 MiB
    if (ws_size >= h1_bytes) {
        float* h1g = (float*)d_ws;
        dim3 g1(16, Nn);
        k1_conv1_kernel<<<g1, 256, 0, stream>>>(x, c1w, c1b, h1g);
        dim3 g2(6, Nn);
        k2_conv2_spline_db_kernel<<<g2, 256, 0, stream>>>(x, h1g, c2w, c2b, out_fx, out_logJ);
    } else {
        dim3 grid(6, Nn);
        csplaq_v4_kernel<<<grid, 256, 0, stream>>>(x, c1w, c1b, c2w, c2b, out_fx, out_logJ);
    }
}

// Round 10
// 424.427 us; speedup vs baseline: 1.7174x; 1.1860x over previous
//
#include <hip/hip_runtime.h>
#include <math.h>

#define Nn 512
#define Ld 64
#define NB 8
#define C1 32
#define C2 25      // 3*NB+1

// ---- exact math (bit-identical to passing round-4/5 kernels) ----
__device__ __forceinline__ float gelu_tanh(float a) {
    float a3 = a * a * a;
    float t = tanhf(0.7978845608028654f * (a + 0.044715f * a3));
    return 0.5f * a * (1.0f + t);
}

__device__ __forceinline__ float softplus_f(float v) {
    return (v > 0.0f) ? v + log1pf(expf(-v)) : log1pf(expf(v));
}

__device__ __forceinline__ float pos_mod_2pi(float v) {
    const float T = 6.2831853071795864769f;
    float r = fmodf(v, T);
    if (r < 0.0f) r += T;
    return r;
}

// async global->LDS DMA, 16B per lane; LDS dest is wave-uniform base + lane*16
__device__ __forceinline__ void gld_lds16(const float* gptr, float* ldsptr) {
    __builtin_amdgcn_global_load_lds(
        (const __attribute__((address_space(1))) void*)gptr,
        (__attribute__((address_space(3))) void*)(uintptr_t)(void*)ldsptr,
        16, 0, 0);
}

// ================= K1: conv1 + gelu -> global h1 [n][c][64][64] =================
// r6 config (unbounded): measured 104 us vs 117 us bounded. UNCHANGED this round.
__global__ __launch_bounds__(256) void k1_conv1_kernel(
    const float* __restrict__ x,
    const float* __restrict__ c1w, const float* __restrict__ c1b,
    float* __restrict__ h1g)
{
    __shared__ float s_cos[8 * 69];
    __shared__ float s_sin[8 * 69];

    const int tid = threadIdx.x;
    const int rb  = blockIdx.x;      // 0..15 -> 4-row band
    const int n   = blockIdx.y;
    const int r0k = rb * 4;
    const float* xn = x + n * 4096;

    for (int idx = tid; idx < 8 * 68; idx += 256) {
        int li = idx / 68, lj = idx - li * 68;
        int gi = (r0k - 2 + li) & 63;
        int gj = (lj - 2) & 63;
        float xv = xn[gi * 64 + gj];
        int pat = (gi + 2 * gj) % 3;
        float sv, cv;
        sincosf(xv, &sv, &cv);
        float fz = (pat == 2) ? 1.0f : 0.0f;
        s_cos[li * 69 + lj] = fz * cv;
        s_sin[li * 69 + lj] = fz * sv;
    }
    __syncthreads();

    const int gj = tid & 63, lrow = tid >> 6;
    const int gi = r0k + lrow;

    float v[18];
    #pragma unroll
    for (int di = 0; di < 3; ++di)
        #pragma unroll
        for (int dj = 0; dj < 3; ++dj) {
            int a = (lrow + 1 + di) * 69 + (gj + 1 + dj);
            v[di * 3 + dj]     = s_cos[a];
            v[9 + di * 3 + dj] = s_sin[a];
        }

    float* outp = h1g + (size_t)n * C1 * 4096 + gi * 64 + gj;
    #pragma unroll 4
    for (int c = 0; c < C1; ++c) {
        const float* w = c1w + c * 18;   // uniform -> s_load
        float a1 = c1b[c];
        #pragma unroll
        for (int t = 0; t < 9; ++t) {    // cos/sin interleaved per tap == r4 order
            a1 = fmaf(v[t],     w[t],     a1);
            a1 = fmaf(v[9 + t], w[9 + t], a1);
        }
        outp[(size_t)c * 4096] = gelu_tanh(a1);
    }
}

// ========== K2: conv2 + spline, dbuf LDS with global_load_lds (m97 pattern) ==========
// No register prefetch (r7/r9 spilled ~300MB scratch). One barrier per chunk;
// async loads issued before compute get the whole compute phase to land, the
// compiler's vmcnt(0)-before-s_barrier drains them at the barrier we need anyway.
// LDS layout lane-linear (f*16B), NO padding — required by global_load_lds.
#define K2CH 4
#define K2PLANE 896         // 14 rows * 64 cols per channel plane (floats)
#define K2NF4  896          // float4 slots per chunk (4 planes * 224)

__global__ __launch_bounds__(256, 5) void k2_conv2_spline_ald_kernel(
    const float* __restrict__ x, const float* __restrict__ h1g,
    const float* __restrict__ c2w, const float* __restrict__ c2b,
    float* __restrict__ out_fx, float* __restrict__ out_logJ)
{
    __shared__ float s_a[K2CH * K2PLANE];   // 14336 B
    __shared__ float s_b[K2CH * K2PLANE];   // 14336 B
    __shared__ float s_red[4];

    const float TWO_PI_F = 6.2831853071795864769f;

    const int tid  = threadIdx.x;
    const int band = blockIdx.x;            // 0..5
    const int n    = blockIdx.y;
    const int r0   = band * 12;
    const int R    = (band == 5) ? 4 : 12;
    const int n_active = (R == 12) ? 256 : 86;
    const float* xn  = x + n * 4096;
    const float* h1n = h1g + (size_t)n * C1 * 4096;

    // active-site mapping: rows 3g,3g+1,3g+2 hold 22,21,21 actives, col≡row mod 3
    int g3 = tid >> 6, u = tid & 63;
    int rsel  = (u >= 22) + (u >= 43);
    int ubase = (rsel == 2) ? 43 : ((rsel == 1) ? 22 : 0);
    int rr = 3 * g3 + rsel;                 // local band row
    int cc = 3 * (u - ubase) + rsel;        // global col
    bool is_act = (tid < n_active);
    int jm = (cc + 63) & 63, jp = (cc + 1) & 63;

    // staging descriptors: slot f covers channel c=f/224, row (f%224)>>4, col4 f&15.
    // Always stage 14 rows (band 5 wraps; extra rows unused). f<896 masks whole waves.
    const float* g0[4]; int loff[4]; bool en[4];
    #pragma unroll
    for (int k = 0; k < 4; ++k) {
        int f = tid + k * 256;
        en[k] = (f < K2NF4);
        int c = f / 224, rem = f - c * 224;
        int grow = (r0 - 1 + (rem >> 4)) & 63;
        g0[k]   = h1n + (size_t)c * 4096 + grow * 64 + (rem & 15) * 4;
        loff[k] = f * 4;                    // float offset, = 16B per slot
    }

    float acc[C2];
    #pragma unroll
    for (int co = 0; co < C2; ++co) acc[co] = c2b[co];

    // prologue: chunk 0 -> buffer A (barrier drains vmcnt)
    #pragma unroll
    for (int k = 0; k < 4; ++k) if (en[k]) gld_lds16(g0[k], s_a + loff[k]);
    __syncthreads();

    int cur = 0;
    for (int c0 = 0; c0 < C1; c0 += K2CH) {
        // issue next chunk's async loads into the other buffer (safe: its previous
        // readers finished at the barrier that ended the last iteration)
        if (c0 + K2CH < C1) {
            const size_t adv = (size_t)(c0 + K2CH) * 4096;
            float* nxt = cur ? s_a : s_b;
            #pragma unroll
            for (int k = 0; k < 4; ++k) if (en[k]) gld_lds16(g0[k] + adv, nxt + loff[k]);
        }
        const float* sbuf = cur ? s_b : s_a;
        if (is_act) {
            #pragma unroll 1
            for (int c = 0; c < K2CH; ++c) {
                int ci = c0 + c;
                float v[9];
                #pragma unroll
                for (int di = 0; di < 3; ++di) {
                    const float* rowp = sbuf + c * K2PLANE + (rr + di) * 64;
                    v[di * 3 + 0] = rowp[jm];
                    v[di * 3 + 1] = rowp[cc];
                    v[di * 3 + 2] = rowp[jp];
                }
                const float* wp = c2w + ci * 9;
                #pragma unroll
                for (int co = 0; co < C2; ++co) {
                    const float* w = wp + co * (C1 * 9);  // uniform -> s_load
                    float a2 = acc[co];
                    #pragma unroll
                    for (int t = 0; t < 9; ++t) a2 = fmaf(v[t], w[t], a2);
                    acc[co] = a2;
                }
            }
        }
        __syncthreads();   // drains the async loads (they had the compute phase to fly)
        cur ^= 1;
    }

    // ---- passive/frozen pass-through ----
    float* outn = out_fx + n * 4096;
    for (int idx = tid; idx < R * 64; idx += 256) {
        int lr = idx >> 6, c = idx & 63;
        int gi = r0 + lr;
        int pat = (gi + 2 * c) % 3;
        float xv = xn[gi * 64 + c];
        if (pat != 0) outn[gi * 64 + c] = xv;
    }

    // ---- spline at the active site (exact math, r4-identical) ----
    float lj_val = 0.0f;
    if (is_act) {
        int gi = r0 + rr;
        float xv = xn[gi * 64 + cc];

        float kx[NB + 1], ky[NB + 1], sar[NB + 1];
        {
            float m = acc[0];
            #pragma unroll
            for (int q = 1; q < NB; ++q) m = fmaxf(m, acc[q]);
            float e[NB], ssum = 0.0f;
            #pragma unroll
            for (int q = 0; q < NB; ++q) { e[q] = expf(acc[q] - m); ssum += e[q]; }
            float inv = TWO_PI_F / ssum;
            float run = 0.0f;
            kx[0] = 0.0f;
            #pragma unroll
            for (int q = 0; q < NB; ++q) { run += e[q]; kx[q + 1] = run * inv; }
        }
        {
            float m = acc[NB];
            #pragma unroll
            for (int q = 1; q < NB; ++q) m = fmaxf(m, acc[NB + q]);
            float e[NB], ssum = 0.0f;
            #pragma unroll
            for (int q = 0; q < NB; ++q) { e[q] = expf(acc[NB + q] - m); ssum += e[q]; }
            float inv = TWO_PI_F / ssum;
            float run = 0.0f;
            ky[0] = 0.0f;
            #pragma unroll
            for (int q = 0; q < NB; ++q) { run += e[q]; ky[q + 1] = run * inv; }
        }
        #pragma unroll
        for (int q = 0; q < NB; ++q) sar[q] = softplus_f(acc[2 * NB + q]);
        sar[NB] = sar[0];
        float t_out = acc[3 * NB];

        float x1 = pos_mod_2pi(xv);
        int k = 0;
        #pragma unroll
        for (int q = 1; q <= NB - 1; ++q) k += (x1 >= kx[q]) ? 1 : 0;

        float kxk = 0.f, kxk1 = 0.f, kyk = 0.f, kyk1 = 0.f, sk = 0.f, sk1 = 0.f;
        #pragma unroll
        for (int q = 0; q <= NB; ++q) {
            if (q == k)     { kxk = kx[q];  kyk = ky[q];  sk  = sar[q]; }
            if (q == k + 1) { kxk1 = kx[q]; kyk1 = ky[q]; sk1 = sar[q]; }
        }

        float wk = kxk1 - kxk;
        float hk = kyk1 - kyk;
        float slope = hk / wk;
        float xi = (x1 - kxk) / wk;
        xi = fminf(fmaxf(xi, 0.0f), 1.0f);
        float om = 1.0f - xi;
        float den = slope + (sk1 + sk - 2.0f * slope) * xi * om;
        float y = kyk + hk * (slope * xi * xi + sk * xi * om) / den;
        float num = slope * slope * (sk1 * xi * xi + 2.0f * slope * xi * om + sk * om * om);
        lj_val = logf(num) - 2.0f * logf(den);

        outn[gi * 64 + cc] = pos_mod_2pi(y + t_out);
    }

    // ---- logJ: wave shuffle -> LDS -> one atomic per block ----
    float r = lj_val;
    #pragma unroll
    for (int off = 32; off > 0; off >>= 1) r += __shfl_down(r, off, 64);
    int lane = tid & 63, wv = tid >> 6;
    if (lane == 0) s_red[wv] = r;
    __syncthreads();
    if (tid == 0)
        atomicAdd(&out_logJ[n], s_red[0] + s_red[1] + s_red[2] + s_red[3]);
}

// ================= fallback: round-4 fused kernel (if ws too small) =================
#define CHUNK 8
#define ICOLS 68
#define ISTR  69
#define IROWSMAX 16
#define HCOLS 66
#define HSTR  67
#define HPLANE 945

__global__ __launch_bounds__(256, 4) void csplaq_v4_kernel(
    const float* __restrict__ x,
    const float* __restrict__ c1w, const float* __restrict__ c1b,
    const float* __restrict__ c2w, const float* __restrict__ c2b,
    float* __restrict__ out_fx, float* __restrict__ out_logJ)
{
    __shared__ float s_cos[IROWSMAX * ISTR];
    __shared__ float s_sin[IROWSMAX * ISTR];
    __shared__ float s_h1[CHUNK * HPLANE];
    __shared__ float s_red[4];

    const float TWO_PI_F = 6.2831853071795864769f;
    const int tid  = threadIdx.x;
    const int band = blockIdx.x;
    const int n    = blockIdx.y;
    const int r0   = band * 12;
    const int R    = (band == 5) ? 4 : 12;
    const int rows_in  = R + 4;
    const int nsite_h  = (R + 2) * HCOLS;
    const int n_active = (R == 12) ? 256 : 86;
    const float* xn = x + n * Ld * Ld;

    for (int idx = tid; idx < rows_in * ICOLS; idx += 256) {
        int li = idx / ICOLS, uu = idx - li * ICOLS;
        int gi = (r0 - 2 + li) & 63;
        int gj = (uu - 2) & 63;
        float xv = xn[gi * Ld + gj];
        int pat = (gi + 2 * gj) % 3;
        float sv, cv;
        sincosf(xv, &sv, &cv);
        float fz = (pat == 2) ? 1.0f : 0.0f;
        s_cos[li * ISTR + uu] = fz * cv;
        s_sin[li * ISTR + uu] = fz * sv;
    }

    int g3 = tid >> 6, u = tid & 63;
    int rsel  = (u >= 22) + (u >= 43);
    int ubase = (rsel == 2) ? 43 : ((rsel == 1) ? 22 : 0);
    int rr = 3 * g3 + rsel;
    int cc = 3 * (u - ubase) + rsel;
    bool is_act = (tid < n_active);

    float acc[C2];
    #pragma unroll
    for (int co = 0; co < C2; ++co) acc[co] = c2b[co];

    for (int c0 = 0; c0 < C1; c0 += CHUNK) {
        __syncthreads();
        for (int s = tid; s < nsite_h; s += 256) {
            int h = s / HCOLS, j = s - h * HCOLS;
            float v[18];
            #pragma unroll
            for (int di = 0; di < 3; ++di)
                #pragma unroll
                for (int dj = 0; dj < 3; ++dj) {
                    int a = (h + di) * ISTR + (j + dj);
                    v[di * 3 + dj]     = s_cos[a];
                    v[9 + di * 3 + dj] = s_sin[a];
                }
            #pragma unroll
            for (int c = 0; c < CHUNK; ++c) {
                const float* w = c1w + (c0 + c) * 18;
                float a1 = c1b[c0 + c];
                #pragma unroll
                for (int t = 0; t < 9; ++t) {
                    a1 = fmaf(v[t],     w[t],     a1);
                    a1 = fmaf(v[9 + t], w[9 + t], a1);
                }
                s_h1[c * HPLANE + h * HSTR + j] = gelu_tanh(a1);
            }
        }
        __syncthreads();
        if (is_act) {
            #pragma unroll 1
            for (int c = 0; c < CHUNK; ++c) {
                int ci = c0 + c;
                float v[9];
                const float* hp = s_h1 + c * HPLANE + rr * HSTR + cc;
                #pragma unroll
                for (int di = 0; di < 3; ++di)
                    #pragma unroll
                    for (int dj = 0; dj < 3; ++dj)
                        v[di * 3 + dj] = hp[di * HSTR + dj];
                const float* wp = c2w + ci * 9;
                #pragma unroll
                for (int co = 0; co < C2; ++co) {
                    const float* w = wp + co * (C1 * 9);
                    float a2 = acc[co];
                    #pragma unroll
                    for (int t = 0; t < 9; ++t) a2 = fmaf(v[t], w[t], a2);
                    acc[co] = a2;
                }
            }
        }
    }

    float* outn = out_fx + n * Ld * Ld;
    for (int idx = tid; idx < R * 64; idx += 256) {
        int lr = idx >> 6, c = idx & 63;
        int gi = r0 + lr;
        int pat = (gi + 2 * c) % 3;
        float xv = xn[gi * Ld + c];
        if (pat != 0) outn[gi * Ld + c] = xv;
    }

    float lj_val = 0.0f;
    if (is_act) {
        int gi = r0 + rr;
        float xv = xn[gi * Ld + cc];
        float kx[NB + 1], ky[NB + 1], sar[NB + 1];
        {
            float m = acc[0];
            #pragma unroll
            for (int q = 1; q < NB; ++q) m = fmaxf(m, acc[q]);
            float e[NB], ssum = 0.0f;
            #pragma unroll
            for (int q = 0; q < NB; ++q) { e[q] = expf(acc[q] - m); ssum += e[q]; }
            float inv = TWO_PI_F / ssum;
            float run = 0.0f;
            kx[0] = 0.0f;
            #pragma unroll
            for (int q = 0; q < NB; ++q) { run += e[q]; kx[q + 1] = run * inv; }
        }
        {
            float m = acc[NB];
            #pragma unroll
            for (int q = 1; q < NB; ++q) m = fmaxf(m, acc[NB + q]);
            float e[NB], ssum = 0.0f;
            #pragma unroll
            for (int q = 0; q < NB; ++q) { e[q] = expf(acc[NB + q] - m); ssum += e[q]; }
            float inv = TWO_PI_F / ssum;
            float run = 0.0f;
            ky[0] = 0.0f;
            #pragma unroll
            for (int q = 0; q < NB; ++q) { run += e[q]; ky[q + 1] = run * inv; }
        }
        #pragma unroll
        for (int q = 0; q < NB; ++q) sar[q] = softplus_f(acc[2 * NB + q]);
        sar[NB] = sar[0];
        float t_out = acc[3 * NB];

        float x1 = pos_mod_2pi(xv);
        int k = 0;
        #pragma unroll
        for (int q = 1; q <= NB - 1; ++q) k += (x1 >= kx[q]) ? 1 : 0;

        float kxk = 0.f, kxk1 = 0.f, kyk = 0.f, kyk1 = 0.f, sk = 0.f, sk1 = 0.f;
        #pragma unroll
        for (int q = 0; q <= NB; ++q) {
            if (q == k)     { kxk = kx[q];  kyk = ky[q];  sk  = sar[q]; }
            if (q == k + 1) { kxk1 = kx[q]; kyk1 = ky[q]; sk1 = sar[q]; }
        }

        float wk = kxk1 - kxk;
        float hk = kyk1 - kyk;
        float slope = hk / wk;
        float xi = (x1 - kxk) / wk;
        xi = fminf(fmaxf(xi, 0.0f), 1.0f);
        float om = 1.0f - xi;
        float den = slope + (sk1 + sk - 2.0f * slope) * xi * om;
        float y = kyk + hk * (slope * xi * xi + sk * xi * om) / den;
        float num = slope * slope * (sk1 * xi * xi + 2.0f * slope * xi * om + sk * om * om);
        lj_val = logf(num) - 2.0f * logf(den);

        outn[gi * Ld + cc] = pos_mod_2pi(y + t_out);
    }

    float r = lj_val;
    #pragma unroll
    for (int off = 32; off > 0; off >>= 1) r += __shfl_down(r, off, 64);
    int lane = tid & 63, wv = tid >> 6;
    if (lane == 0) s_red[wv] = r;
    __syncthreads();
    if (tid == 0)
        atomicAdd(&out_logJ[n], s_red[0] + s_red[1] + s_red[2] + s_red[3]);
}

extern "C" void kernel_launch(void* const* d_in, const int* in_sizes, int n_in,
                              void* d_out, int out_size, void* d_ws, size_t ws_size,
                              hipStream_t stream) {
    const float* x   = (const float*)d_in[0];
    // d_in[1..3] masks: recomputed analytically ((i+2j)%3) -> exact
    const float* c1w = (const float*)d_in[4];
    const float* c1b = (const float*)d_in[5];
    const float* c2w = (const float*)d_in[6];
    const float* c2b = (const float*)d_in[7];

    float* out_fx   = (float*)d_out;
    float* out_logJ = out_fx + (size_t)Nn * Ld * Ld;

    hipMemsetAsync(out_logJ, 0, Nn * sizeof(float), stream);

    const size_t h1_bytes = (size_t)Nn * C1 * Ld * Ld * sizeof(float);  // 256 MiB
    if (ws_size >= h1_bytes) {
        float* h1g = (float*)d_ws;
        dim3 g1(16, Nn);
        k1_conv1_kernel<<<g1, 256, 0, stream>>>(x, c1w, c1b, h1g);
        dim3 g2(6, Nn);
        k2_conv2_spline_ald_kernel<<<g2, 256, 0, stream>>>(x, h1g, c2w, c2b, out_fx, out_logJ);
    } else {
        dim3 grid(6, Nn);
        csplaq_v4_kernel<<<grid, 256, 0, stream>>>(x, c1w, c1b, c2w, c2b, out_fx, out_logJ);
    }
}